// Round 13
// baseline (589.569 us; speedup 1.0000x reference)
//
#include <hip/hip_runtime.h>

typedef unsigned short u16;
typedef unsigned int   u32;
typedef short bf16x8 __attribute__((ext_vector_type(8)));
typedef float f32x2  __attribute__((ext_vector_type(2)));
typedef float f32x4  __attribute__((ext_vector_type(4)));
typedef float f32x16 __attribute__((ext_vector_type(16)));

#define NB  32
#define NQ  1024
#define GS  1024
#define NH  8
#define SCQ (0.25f * 1.4426950408889634f)   /* 1/sqrt(16) * log2(e) */
#define MBIG (-1.0e30f)

#define MFMA16(a, b, c) __builtin_amdgcn_mfma_f32_16x16x32_bf16(a, b, c, 0, 0, 0)
#define MFMA32(a, b, c) __builtin_amdgcn_mfma_f32_32x32x16_bf16(a, b, c, 0, 0, 0)

__device__ __forceinline__ u16 f2bf(float f) {  // RNE float->bf16 bits
    u32 u = __float_as_uint(f);
    return (u16)((u + 0x7fffu + ((u >> 16) & 1u)) >> 16);
}
// packed round-half-up: result = bf(a) | bf(b)<<16, 3 VALU ops via v_perm_b32
__device__ __forceinline__ u32 pk2bf(float a, float b) {
    u32 ua = __float_as_uint(a) + 0x8000u;
    u32 ub = __float_as_uint(b) + 0x8000u;
    return __builtin_amdgcn_perm(ub, ua, 0x07060302u);  // bytes [b3 b2 a3 a2]
}

// ---------------------------------------------------------------------------
// MFMA GEMM v7 (proven): C[128x128] = A[128x128] * W^T, K=128.
// NO A-LDS staging; W through LDS; epilogue buffer aliases Ws.
// MODE 0: bf16 out row-major.
// MODE 2: bf16 out transposed per batch with sigma slot permutation.
// ---------------------------------------------------------------------------
template <int MODE>
__device__ __forceinline__ void mgemm(const float* __restrict__ Ain,
                                      const float* __restrict__ Wraw,
                                      float wsc,
                                      u16* __restrict__ outb,
                                      u16* Ws, int row0) {
    const int t    = threadIdx.x;
    const int wv   = t >> 6;
    const int lane = t & 63;
    const int quad = lane >> 4;
    const int c    = lane & 15;

    // W stage: Ws[col*136 + k] = bf16(W[h][k][e]*wsc), col = 16h+e.
#pragma unroll
    for (int g0 = 0; g0 < 2048; g0 += 256) {
        int idx  = g0 + t;
        int hk   = idx >> 1, half = idx & 1;
        int k    = hk & 127;
        int col0 = (hk >> 7) * 16 + half * 8;
        const float4* wp = (const float4*)&Wraw[hk * 16 + half * 8];
        float4 w0 = wp[0], w1 = wp[1];
        Ws[(col0 + 0) * 136 + k] = f2bf(w0.x * wsc);
        Ws[(col0 + 1) * 136 + k] = f2bf(w0.y * wsc);
        Ws[(col0 + 2) * 136 + k] = f2bf(w0.z * wsc);
        Ws[(col0 + 3) * 136 + k] = f2bf(w0.w * wsc);
        Ws[(col0 + 4) * 136 + k] = f2bf(w1.x * wsc);
        Ws[(col0 + 5) * 136 + k] = f2bf(w1.y * wsc);
        Ws[(col0 + 6) * 136 + k] = f2bf(w1.z * wsc);
        Ws[(col0 + 7) * 136 + k] = f2bf(w1.w * wsc);
    }

    // A fragments: rows wv*32+c and wv*32+16+c, k-octet kt*32+quad*8.
    const float* a0p = &Ain[(size_t)(row0 + wv * 32 + c) * 128];
    const float* a1p = &Ain[(size_t)(row0 + wv * 32 + 16 + c) * 128];
    bf16x8 af0[4], af1[4];
#pragma unroll
    for (int kt = 0; kt < 4; ++kt) {
        int k0 = kt * 32 + quad * 8;
        float4 x0 = *(const float4*)&a0p[k0];
        float4 x1 = *(const float4*)&a0p[k0 + 4];
        float4 y0 = *(const float4*)&a1p[k0];
        float4 y1 = *(const float4*)&a1p[k0 + 4];
        int4 p0, p1;
        p0.x = (int)pk2bf(x0.x, x0.y);  p0.y = (int)pk2bf(x0.z, x0.w);
        p0.z = (int)pk2bf(x1.x, x1.y);  p0.w = (int)pk2bf(x1.z, x1.w);
        p1.x = (int)pk2bf(y0.x, y0.y);  p1.y = (int)pk2bf(y0.z, y0.w);
        p1.z = (int)pk2bf(y1.x, y1.y);  p1.w = (int)pk2bf(y1.z, y1.w);
        __builtin_memcpy(&af0[kt], &p0, 16);
        __builtin_memcpy(&af1[kt], &p1, 16);
    }
    __syncthreads();                     // Ws ready

    const f32x4 zf = {0.f, 0.f, 0.f, 0.f};
    f32x4 acc[2][8];
#pragma unroll
    for (int s = 0; s < 2; ++s)
#pragma unroll
        for (int j = 0; j < 8; ++j) acc[s][j] = zf;

#pragma unroll
    for (int kt = 0; kt < 4; ++kt) {
#pragma unroll
        for (int j = 0; j < 8; ++j) {
            bf16x8 bfr = *(const bf16x8*)&Ws[(j * 16 + c) * 136 + kt * 32 + quad * 8];
            acc[0][j] = MFMA16(af0[kt], bfr, acc[0][j]);
            acc[1][j] = MFMA16(af1[kt], bfr, acc[1][j]);
        }
    }

    // ---- epilogue via LDS (aliases Ws): scatter bf16, coalesced int4 out ----
    __syncthreads();                     // all Ws reads complete
    u16* Os = Ws;
#pragma unroll
    for (int s = 0; s < 2; ++s)
#pragma unroll
        for (int j = 0; j < 8; ++j)
#pragma unroll
            for (int r = 0; r < 4; ++r) {
                int lrow = wv * 32 + s * 16 + quad * 4 + r;
                int col  = j * 16 + c;
                u16 v = f2bf(acc[s][j][r]);
                if (MODE == 0) {
                    Os[lrow * 136 + col] = v;
                } else {
                    int u   = lrow & 15;
                    int sw  = ((u >> 2) ^ (u >> 3)) & 1;     // sigma: swap quads 1<->2
                    int tbp = lrow ^ (sw ? 12 : 0);
                    Os[col * 136 + tbp] = v;
                }
            }
    __syncthreads();

    if (MODE == 0) {
#pragma unroll
        for (int it = 0; it < 8; ++it) {
            int chunk = it * 256 + t;
            int lrow = chunk >> 4, c0 = (chunk & 15) * 8;
            *(int4*)&outb[(size_t)(row0 + lrow) * 128 + c0] =
                *(const int4*)&Os[lrow * 136 + c0];
        }
    } else {
        int bI = row0 >> 10, tb0 = row0 & 1023;
#pragma unroll
        for (int it = 0; it < 8; ++it) {
            int chunk = it * 256 + t;
            int col = chunk >> 4, t0 = (chunk & 15) * 8;
            *(int4*)&outb[(size_t)bI * (128 * 1024) + (size_t)col * 1024 + tb0 + t0] =
                *(const int4*)&Os[col * 136 + t0];
        }
    }
}

__global__ __launch_bounds__(256, 3) void proj_mfma(const float* __restrict__ q,
                                                    const float* __restrict__ h,
                                                    const float* __restrict__ Wq,
                                                    const float* __restrict__ Wk,
                                                    const float* __restrict__ Wv,
                                                    const float* __restrict__ Wout,
                                                    u16* __restrict__ Qb,
                                                    u16* __restrict__ Kb,
                                                    u16* __restrict__ Vtg,
                                                    u16* __restrict__ Wob) {
    __shared__ u16 Ws[128 * 136];
    int y = blockIdx.y;
    if (y == 3) {
        // Wob prep: [d][he] = Wout[he>>4][he&15][d], blocks x<64
        if (blockIdx.x < 64) {
            int i = blockIdx.x * 256 + threadIdx.x;    // 0..16383
            int d = i >> 7, he = i & 127;
            Wob[i] = f2bf(Wout[(he >> 4) * 2048 + (he & 15) * 128 + d]);
        }
        return;
    }
    int row0 = blockIdx.x * 128;
    if (y == 0)      mgemm<0>(q, Wq, SCQ,  Qb,  Ws, row0);
    else if (y == 1) mgemm<0>(h, Wk, 1.0f, Kb,  Ws, row0);
    else             mgemm<2>(h, Wv, 1.0f, Vtg, Ws, row0);
}

// ---------------------------------------------------------------------------
// MFMA flash attention + fused out-projection, v13 = v9 per-wave compute
// with a 16-WAVE block (QBLK=64 by waves, NOT by per-thread state — the
// v10/v11 register cliff is avoided: per-thread live set SHRINKS, 1 staging
// int4 each for K/V/mask instead of 2).
//   waves 0-7:  heads 0-7 on q-rows q0..q0+31   (v9 body verbatim)
//   waves 8-15: heads 0-7 on q-rows q0+32..q0+63
// Each K/V/mask tile staged ONCE per 64 q-rows: per-q-row staging, barrier
// and L2 traffic halve. 512 blocks = exactly 2/CU (32 waves = full slots).
// LDS: Kt 17408 (reused as 64-row Hs) + Vtt 18432 + Mf[64][68] 17408
//    = 53248 B -> 2 blocks/CU. (1024,8) caps VGPR at 64; v9 measured 60.
// ---------------------------------------------------------------------------
__global__ __launch_bounds__(1024, 8) void flash_mfma(const u16* __restrict__ Qb,
                                                      const u16* __restrict__ Kb,
                                                      const u16* __restrict__ Vtg,
                                                      const int* __restrict__ mask,
                                                      const u16* __restrict__ Wob,
                                                      float* __restrict__ out) {
    __shared__ u16 Kt[64 * 136];        // [key][dim]; reused as 64-row Hs
    __shared__ u16 Vtt[128 * 72];       // [dim][slot], sigma-permuted slots
    __shared__ float Mf[64 * 68];       // mask addend [q 0..63][key 0..63]

    const int b    = blockIdx.x;
    const int q0   = blockIdx.y * 64;
    const int t    = threadIdx.x;
    const int wave = t >> 6;            // 0..15
    const int hh   = wave & 7;          // head
    const int qg   = wave >> 3;         // q-group 0/1
    const int lane = t & 63;
    const int quad = lane >> 4;         // 0..3
    const int c    = lane & 15;
    const int qq   = lane & 31;         // q-row within group / key row
    const int hi   = lane >> 5;         // k-slice select for 32x32x16 frags
    const int qrow = qg * 32 + qq;      // q-row within block (0..63)

    // Q fragment (B operand of swapped score MFMA): full 16-dim head slice
    bf16x8 qf = *(const bf16x8*)&Qb[((size_t)b * NQ + q0 + qrow) * 128 +
                                    hh * 16 + hi * 8];

    f32x16 O32;
#pragma unroll
    for (int r = 0; r < 16; ++r) O32[r] = 0.f;
    float lsum = 0.f;

    // staging indices (1024 threads, 1 int4 each)
    const int skey = t >> 4;            // K: key 0..63, dim octet (t&15)*8
    const int sd0  = (t & 15) * 8;
    const int vdim = t >> 3;            // V: dim 0..127, slot octet (t&7)*8
    const int vs0  = (t & 7) * 8;
    const int mrow = t >> 4;            // M: q-row 0..63, key quad (t&15)*4
    const int mk0  = (t & 15) * 4;

    const u16* Kptr = &Kb[((size_t)b * GS + skey) * 128 + sd0];
    const u16* Vptr = &Vtg[(size_t)b * (128 * 1024) + (size_t)vdim * 1024 + vs0];
    const int* Mptr = &mask[((size_t)b * NQ + q0 + mrow) * GS + mk0];

    int4 kreg = *(const int4*)Kptr;
    int4 vreg = *(const int4*)Vptr;
    int4 mreg = *(const int4*)Mptr;

    for (int g0 = 0; g0 < GS; g0 += 64) {
        __syncthreads();
        *(int4*)&Kt[skey * 136 + sd0] = kreg;
        *(int4*)&Vtt[vdim * 72 + vs0] = vreg;
        f32x4 mm;
        mm.x = mreg.x ? MBIG : 0.f;
        mm.y = mreg.y ? MBIG : 0.f;
        mm.z = mreg.z ? MBIG : 0.f;
        mm.w = mreg.w ? MBIG : 0.f;
        *(f32x4*)&Mf[mrow * 68 + mk0] = mm;
        __syncthreads();

        if (g0 + 64 < GS) {
            Kptr += 64 * 128;  kreg = *(const int4*)Kptr;
            Vptr += 64;        vreg = *(const int4*)Vptr;
            Mptr += 64;        mreg = *(const int4*)Mptr;
        }

        // two independent swapped-score chains: D[key][q], K=16 head dim
        bf16x8 kf0 = *(const bf16x8*)&Kt[qq * 136 + hh * 16 + hi * 8];
        bf16x8 kf1 = *(const bf16x8*)&Kt[(32 + qq) * 136 + hh * 16 + hi * 8];
        f32x16 c0, c1;
#pragma unroll
        for (int blk = 0; blk < 4; ++blk) {
            f32x4 m0 = *(const f32x4*)&Mf[qrow * 68 + 8 * blk + 4 * hi];
            f32x4 m1 = *(const f32x4*)&Mf[qrow * 68 + 32 + 8 * blk + 4 * hi];
            c0[4 * blk + 0] = m0.x;  c0[4 * blk + 1] = m0.y;
            c0[4 * blk + 2] = m0.z;  c0[4 * blk + 3] = m0.w;
            c1[4 * blk + 0] = m1.x;  c1[4 * blk + 1] = m1.y;
            c1[4 * blk + 2] = m1.z;  c1[4 * blk + 3] = m1.w;
        }
        f32x16 s0 = MFMA32(kf0, qf, c0);
        f32x16 s1 = MFMA32(kf1, qf, c1);

        bf16x8 vf0 = *(const bf16x8*)&Vtt[(hh * 16 + c) * 72 + hi * 8];
        bf16x8 vf1 = *(const bf16x8*)&Vtt[(hh * 16 + c) * 72 + 16 + hi * 8];
        bf16x8 vf2 = *(const bf16x8*)&Vtt[(hh * 16 + c) * 72 + 32 + hi * 8];
        bf16x8 vf3 = *(const bf16x8*)&Vtt[(hh * 16 + c) * 72 + 48 + hi * 8];

        // chunk 0: exp -> lsum -> pack -> PV (keys 0..31), all in-register
#pragma unroll
        for (int r = 0; r < 16; ++r) s0[r] = __builtin_amdgcn_exp2f(s0[r]);
        lsum += ((s0[0] + s0[1]) + (s0[2] + s0[3])) + ((s0[4] + s0[5]) + (s0[6] + s0[7])) +
                (((s0[8] + s0[9]) + (s0[10] + s0[11])) + ((s0[12] + s0[13]) + (s0[14] + s0[15])));
        {
            int4 pa, pb;
            pa.x = (int)pk2bf(s0[0],  s0[1]);  pa.y = (int)pk2bf(s0[2],  s0[3]);
            pa.z = (int)pk2bf(s0[4],  s0[5]);  pa.w = (int)pk2bf(s0[6],  s0[7]);
            pb.x = (int)pk2bf(s0[8],  s0[9]);  pb.y = (int)pk2bf(s0[10], s0[11]);
            pb.z = (int)pk2bf(s0[12], s0[13]); pb.w = (int)pk2bf(s0[14], s0[15]);
            bf16x8 p0, p1;
            __builtin_memcpy(&p0, &pa, 16);
            __builtin_memcpy(&p1, &pb, 16);
            O32 = MFMA32(vf0, p0, O32);
            O32 = MFMA32(vf1, p1, O32);
        }

        // chunk 1: keys 32..63
#pragma unroll
        for (int r = 0; r < 16; ++r) s1[r] = __builtin_amdgcn_exp2f(s1[r]);
        lsum += ((s1[0] + s1[1]) + (s1[2] + s1[3])) + ((s1[4] + s1[5]) + (s1[6] + s1[7])) +
                (((s1[8] + s1[9]) + (s1[10] + s1[11])) + ((s1[12] + s1[13]) + (s1[14] + s1[15])));
        {
            int4 pa, pb;
            pa.x = (int)pk2bf(s1[0],  s1[1]);  pa.y = (int)pk2bf(s1[2],  s1[3]);
            pa.z = (int)pk2bf(s1[4],  s1[5]);  pa.w = (int)pk2bf(s1[6],  s1[7]);
            pb.x = (int)pk2bf(s1[8],  s1[9]);  pb.y = (int)pk2bf(s1[10], s1[11]);
            pb.z = (int)pk2bf(s1[12], s1[13]); pb.w = (int)pk2bf(s1[14], s1[15]);
            bf16x8 p2, p3;
            __builtin_memcpy(&p2, &pa, 16);
            __builtin_memcpy(&p3, &pb, 16);
            O32 = MFMA32(vf2, p2, O32);
            O32 = MFMA32(vf3, p3, O32);
        }
    }

    // per-lane q-row denominator: combine hi halves
    lsum += __shfl_xor(lsum, 32);
    float rl = (lsum > 0.f) ? 1.f / lsum : 0.f;

    // O32 reg r (r<8) holds O^T[dim][q=qrow]: dims r<4: 4hi+r ; r>=4: 8+4hi+(r-4)
    u32 h0 = pk2bf(O32[0] * rl, O32[1] * rl);
    u32 h1 = pk2bf(O32[2] * rl, O32[3] * rl);
    u32 h2 = pk2bf(O32[4] * rl, O32[5] * rl);
    u32 h3 = pk2bf(O32[6] * rl, O32[7] * rl);
    __syncthreads();                    // all Kt/Vtt reads done (Hs aliases Kt)
    u16* Hs = Kt;
    int2 ha; ha.x = (int)h0; ha.y = (int)h1;
    int2 hb; hb.x = (int)h2; hb.y = (int)h3;
    *(int2*)&Hs[qrow * 136 + hh * 16 + 4 * hi]     = ha;
    *(int2*)&Hs[qrow * 136 + hh * 16 + 8 + 4 * hi] = hb;
    __syncthreads();

    // fused out-projection: wave (hh,qg) computes out cols hh*16..+15 for
    // rows qg*32 + s*16 .. (s = 0,1)
    const f32x4 zf = {0.f, 0.f, 0.f, 0.f};
    f32x4 oacc[2] = {zf, zf};
#pragma unroll
    for (int kt = 0; kt < 4; ++kt) {
        bf16x8 bfr = *(const bf16x8*)&Wob[(hh * 16 + c) * 128 + kt * 32 + quad * 8];
#pragma unroll
        for (int s = 0; s < 2; ++s) {
            bf16x8 af = *(const bf16x8*)&Hs[(qg * 32 + s * 16 + c) * 136 +
                                            kt * 32 + quad * 8];
            oacc[s] = MFMA16(af, bfr, oacc[s]);
        }
    }
#pragma unroll
    for (int s = 0; s < 2; ++s)
#pragma unroll
        for (int r = 0; r < 4; ++r)
            out[((size_t)b * NQ + q0 + qg * 32 + s * 16 + quad * 4 + r) * 128 +
                hh * 16 + c] = oacc[s][r];
}

extern "C" void kernel_launch(void* const* d_in, const int* in_sizes, int n_in,
                              void* d_out, int out_size, void* d_ws, size_t ws_size,
                              hipStream_t stream) {
    const float* q    = (const float*)d_in[0];
    const float* h    = (const float*)d_in[1];
    const int*   mask = (const int*)d_in[2];
    const float* Wq   = (const float*)d_in[3];
    const float* Wk   = (const float*)d_in[4];
    const float* Wv   = (const float*)d_in[5];
    const float* Wout = (const float*)d_in[6];
    float* out = (float*)d_out;

    const size_t NTOK = (size_t)NB * NQ;     // 32768
    u16* Qb  = (u16*)d_ws;                   // 8 MB each
    u16* Kb  = Qb + NTOK * 128;
    u16* Vtg = Kb + NTOK * 128;              // V^T per batch, sigma-permuted slots
    u16* Wob = Vtg + NTOK * 128;             // prepped Wout, 32 KB

    proj_mfma<<<dim3(256, 4), 256, 0, stream>>>(q, h, Wq, Wk, Wv, Wout,
                                                Qb, Kb, Vtg, Wob);
    flash_mfma<<<dim3(NB, NQ / 64), 1024, 0, stream>>>(Qb, Kb, Vtg, mask,
                                                       Wob, out);
}

// Round 14
// 274.980 us; speedup vs baseline: 2.1440x; 2.1440x over previous
//
#include <hip/hip_runtime.h>

typedef unsigned short u16;
typedef unsigned int   u32;
typedef short bf16x8 __attribute__((ext_vector_type(8)));
typedef float f32x2  __attribute__((ext_vector_type(2)));
typedef float f32x4  __attribute__((ext_vector_type(4)));
typedef float f32x16 __attribute__((ext_vector_type(16)));

#define NB  32
#define NQ  1024
#define GS  1024
#define NH  8
#define SCQ (0.25f * 1.4426950408889634f)   /* 1/sqrt(16) * log2(e) */
#define MBIG (-1.0e30f)

#define MFMA16(a, b, c) __builtin_amdgcn_mfma_f32_16x16x32_bf16(a, b, c, 0, 0, 0)
#define MFMA32(a, b, c) __builtin_amdgcn_mfma_f32_32x32x16_bf16(a, b, c, 0, 0, 0)

__device__ __forceinline__ u16 f2bf(float f) {  // RNE float->bf16 bits
    u32 u = __float_as_uint(f);
    return (u16)((u + 0x7fffu + ((u >> 16) & 1u)) >> 16);
}
// packed round-half-up: result = bf(a) | bf(b)<<16, 3 VALU ops via v_perm_b32
__device__ __forceinline__ u32 pk2bf(float a, float b) {
    u32 ua = __float_as_uint(a) + 0x8000u;
    u32 ub = __float_as_uint(b) + 0x8000u;
    return __builtin_amdgcn_perm(ub, ua, 0x07060302u);  // bytes [b3 b2 a3 a2]
}

// ---------------------------------------------------------------------------
// MFMA GEMM v14: C[128x128] = A[128x128] * W^T, K=128.
// vs v7: (a) A-fragment global loads issued FIRST (HBM latency hides under
// the W-stage conversion work); (b) W-stage emits ONE ds_write_b128 per
// thread-iter (was 8 scattered ds_write_b16) — identical layout, identical
// f2bf rounding -> bit-identical output, pure issue/latency win.
// MODE 0: bf16 out row-major.
// MODE 2: bf16 out transposed per batch with sigma slot permutation
//         (swap quads 1<->2) so flash's in-register P feeds PV directly.
// ---------------------------------------------------------------------------
template <int MODE>
__device__ __forceinline__ void mgemm(const float* __restrict__ Ain,
                                      const float* __restrict__ Wraw,
                                      float wsc,
                                      u16* __restrict__ outb,
                                      u16* Ws, int row0) {
    const int t    = threadIdx.x;
    const int wv   = t >> 6;
    const int lane = t & 63;
    const int quad = lane >> 4;
    const int c    = lane & 15;

    // ---- A fragments FIRST: rows wv*32+c and wv*32+16+c, k-octet kt*32+quad*8
    const float* a0p = &Ain[(size_t)(row0 + wv * 32 + c) * 128];
    const float* a1p = &Ain[(size_t)(row0 + wv * 32 + 16 + c) * 128];
    bf16x8 af0[4], af1[4];
#pragma unroll
    for (int kt = 0; kt < 4; ++kt) {
        int k0 = kt * 32 + quad * 8;
        float4 x0 = *(const float4*)&a0p[k0];
        float4 x1 = *(const float4*)&a0p[k0 + 4];
        float4 y0 = *(const float4*)&a1p[k0];
        float4 y1 = *(const float4*)&a1p[k0 + 4];
        int4 p0, p1;
        p0.x = (int)pk2bf(x0.x, x0.y);  p0.y = (int)pk2bf(x0.z, x0.w);
        p0.z = (int)pk2bf(x1.x, x1.y);  p0.w = (int)pk2bf(x1.z, x1.w);
        p1.x = (int)pk2bf(y0.x, y0.y);  p1.y = (int)pk2bf(y0.z, y0.w);
        p1.z = (int)pk2bf(y1.x, y1.y);  p1.w = (int)pk2bf(y1.z, y1.w);
        __builtin_memcpy(&af0[kt], &p0, 16);
        __builtin_memcpy(&af1[kt], &p1, 16);
    }

    // ---- W stage: Ws[col*136 + k] = f2bf(W[h][k][e]*wsc), col = 16h+e.
    // thread-iter owns (col, k-octet): 8 strided dword reads (64B-coalesced
    // per 16-lane group), one b128 LDS write.
#pragma unroll
    for (int g0 = 0; g0 < 2048; g0 += 256) {
        int idx = g0 + t;
        int col = idx & 127;
        int k0  = (idx >> 7) * 8;
        const float* wsrc = &Wraw[(col >> 4) * 2048 + (col & 15)];
        float w0 = wsrc[(k0 + 0) * 16], w1 = wsrc[(k0 + 1) * 16];
        float w2 = wsrc[(k0 + 2) * 16], w3 = wsrc[(k0 + 3) * 16];
        float w4 = wsrc[(k0 + 4) * 16], w5 = wsrc[(k0 + 5) * 16];
        float w6 = wsrc[(k0 + 6) * 16], w7 = wsrc[(k0 + 7) * 16];
        int4 pk;
        pk.x = (int)((u32)f2bf(w0 * wsc) | ((u32)f2bf(w1 * wsc) << 16));
        pk.y = (int)((u32)f2bf(w2 * wsc) | ((u32)f2bf(w3 * wsc) << 16));
        pk.z = (int)((u32)f2bf(w4 * wsc) | ((u32)f2bf(w5 * wsc) << 16));
        pk.w = (int)((u32)f2bf(w6 * wsc) | ((u32)f2bf(w7 * wsc) << 16));
        *(int4*)&Ws[col * 136 + k0] = pk;
    }
    __syncthreads();                     // Ws ready

    const f32x4 zf = {0.f, 0.f, 0.f, 0.f};
    f32x4 acc[2][8];
#pragma unroll
    for (int s = 0; s < 2; ++s)
#pragma unroll
        for (int j = 0; j < 8; ++j) acc[s][j] = zf;

#pragma unroll
    for (int kt = 0; kt < 4; ++kt) {
#pragma unroll
        for (int j = 0; j < 8; ++j) {
            bf16x8 bfr = *(const bf16x8*)&Ws[(j * 16 + c) * 136 + kt * 32 + quad * 8];
            acc[0][j] = MFMA16(af0[kt], bfr, acc[0][j]);
            acc[1][j] = MFMA16(af1[kt], bfr, acc[1][j]);
        }
    }

    // ---- epilogue via LDS (aliases Ws): scatter bf16, coalesced int4 out ----
    __syncthreads();                     // all Ws reads complete
    u16* Os = Ws;
#pragma unroll
    for (int s = 0; s < 2; ++s)
#pragma unroll
        for (int j = 0; j < 8; ++j)
#pragma unroll
            for (int r = 0; r < 4; ++r) {
                int lrow = wv * 32 + s * 16 + quad * 4 + r;
                int col  = j * 16 + c;
                u16 v = f2bf(acc[s][j][r]);
                if (MODE == 0) {
                    Os[lrow * 136 + col] = v;
                } else {
                    int u   = lrow & 15;
                    int sw  = ((u >> 2) ^ (u >> 3)) & 1;     // sigma: swap quads 1<->2
                    int tbp = lrow ^ (sw ? 12 : 0);
                    Os[col * 136 + tbp] = v;
                }
            }
    __syncthreads();

    if (MODE == 0) {
#pragma unroll
        for (int it = 0; it < 8; ++it) {
            int chunk = it * 256 + t;
            int lrow = chunk >> 4, c0 = (chunk & 15) * 8;
            *(int4*)&outb[(size_t)(row0 + lrow) * 128 + c0] =
                *(const int4*)&Os[lrow * 136 + c0];
        }
    } else {
        int bI = row0 >> 10, tb0 = row0 & 1023;
#pragma unroll
        for (int it = 0; it < 8; ++it) {
            int chunk = it * 256 + t;
            int col = chunk >> 4, t0 = (chunk & 15) * 8;
            *(int4*)&outb[(size_t)bI * (128 * 1024) + (size_t)col * 1024 + tb0 + t0] =
                *(const int4*)&Os[col * 136 + t0];
        }
    }
}

__global__ __launch_bounds__(256, 3) void proj_mfma(const float* __restrict__ q,
                                                    const float* __restrict__ h,
                                                    const float* __restrict__ Wq,
                                                    const float* __restrict__ Wk,
                                                    const float* __restrict__ Wv,
                                                    const float* __restrict__ Wout,
                                                    u16* __restrict__ Qb,
                                                    u16* __restrict__ Kb,
                                                    u16* __restrict__ Vtg,
                                                    u16* __restrict__ Wob) {
    __shared__ u16 Ws[128 * 136];
    int y = blockIdx.y;
    if (y == 3) {
        // Wob prep: [d][he] = Wout[he>>4][he&15][d], blocks x<64
        if (blockIdx.x < 64) {
            int i = blockIdx.x * 256 + threadIdx.x;    // 0..16383
            int d = i >> 7, he = i & 127;
            Wob[i] = f2bf(Wout[(he >> 4) * 2048 + (he & 15) * 128 + d]);
        }
        return;
    }
    int row0 = blockIdx.x * 128;
    if (y == 0)      mgemm<0>(q, Wq, SCQ,  Qb,  Ws, row0);
    else if (y == 1) mgemm<0>(h, Wk, 1.0f, Kb,  Ws, row0);
    else             mgemm<2>(h, Wv, 1.0f, Vtg, Ws, row0);
}

// ---------------------------------------------------------------------------
// MFMA flash attention + fused out-projection, v9 (PROVEN: flash 94-96 us,
// reproduced rounds 9 and 12). v4 score path (Mf FLOAT mask staging) +
// in-register PV (pack->MFMA32, sigma-permuted V). KVBLK=64, double-barrier
// staging, 1-tile prefetch. ~60 live VGPR at (512,4): v8 (+VALU mask), v10
// (+QBLK state), v11 (+dbuf unroll), v13 (wave-scaled QBLK, 64-VGPR cap)
// all refuted — each crossed the register cliff and scratched. This is the
// plateau structure at this occupancy.
// LDS: 17408 (Kt, rows 0..31 reused as Hs) + 18432 (Vtt) + 8704 (Mf)
//    = 44544 B -> 3 blocks/CU.
// ---------------------------------------------------------------------------
__global__ __launch_bounds__(512, 4) void flash_mfma(const u16* __restrict__ Qb,
                                                     const u16* __restrict__ Kb,
                                                     const u16* __restrict__ Vtg,
                                                     const int* __restrict__ mask,
                                                     const u16* __restrict__ Wob,
                                                     float* __restrict__ out) {
    __shared__ u16 Kt[64 * 136];        // [key][dim]; rows 0..31 reused as Hs
    __shared__ u16 Vtt[128 * 72];       // [dim][slot], sigma-permuted slots
    __shared__ float Mf[32 * 68];       // mask addend [q][key 0..63]

    const int b    = blockIdx.x;
    const int q0   = blockIdx.y * 32;
    const int t    = threadIdx.x;
    const int hh   = t >> 6;
    const int lane = t & 63;
    const int quad = lane >> 4;         // 0..3
    const int c    = lane & 15;
    const int qq   = lane & 31;         // score col (q-row) / A-frag row (key)
    const int hi   = lane >> 5;         // k-slice select for 32x32x16 frags

    // Q fragment (B operand of swapped score MFMA): full 16-dim head slice
    bf16x8 qf = *(const bf16x8*)&Qb[((size_t)b * NQ + q0 + qq) * 128 +
                                    hh * 16 + hi * 8];

    f32x16 O32;
#pragma unroll
    for (int r = 0; r < 16; ++r) O32[r] = 0.f;
    float lsum = 0.f;

    // staging indices
    const int skey = t >> 4;            // K: key 0..31 (+32), dim octet (t&15)*8
    const int sd0  = (t & 15) * 8;
    const int vdim = t >> 2;            // V: dim 0..127, slot octet (t&3)*8 (+32)
    const int vs0  = (t & 3) * 8;
    const int mrow = t >> 4;            // M: q-row 0..31, key pair (t&15)*2 (+32)
    const int mk0  = (t & 15) * 2;

    const u16* Kptr = &Kb[((size_t)b * GS + skey) * 128 + sd0];
    const u16* Vptr = &Vtg[(size_t)b * (128 * 1024) + (size_t)vdim * 1024 + vs0];
    const int* Mptr = &mask[((size_t)b * NQ + q0 + mrow) * GS + mk0];

    int4 kreg0 = *(const int4*)Kptr;
    int4 kreg1 = *(const int4*)(Kptr + 32 * 128);
    int4 vreg0 = *(const int4*)Vptr;
    int4 vreg1 = *(const int4*)(Vptr + 32);
    int2 mreg0 = *(const int2*)Mptr;
    int2 mreg1 = *(const int2*)(Mptr + 32);

    for (int g0 = 0; g0 < GS; g0 += 64) {
        __syncthreads();
        *(int4*)&Kt[skey * 136 + sd0]        = kreg0;
        *(int4*)&Kt[(32 + skey) * 136 + sd0] = kreg1;
        *(int4*)&Vtt[vdim * 72 + vs0]        = vreg0;
        *(int4*)&Vtt[vdim * 72 + 32 + vs0]   = vreg1;
        f32x2 mm0, mm1;
        mm0.x = mreg0.x ? MBIG : 0.f;
        mm0.y = mreg0.y ? MBIG : 0.f;
        mm1.x = mreg1.x ? MBIG : 0.f;
        mm1.y = mreg1.y ? MBIG : 0.f;
        *(f32x2*)&Mf[mrow * 68 + mk0]      = mm0;
        *(f32x2*)&Mf[mrow * 68 + 32 + mk0] = mm1;
        __syncthreads();

        if (g0 + 64 < GS) {
            Kptr += 64 * 128;
            kreg0 = *(const int4*)Kptr;
            kreg1 = *(const int4*)(Kptr + 32 * 128);
            Vptr += 64;
            vreg0 = *(const int4*)Vptr;
            vreg1 = *(const int4*)(Vptr + 32);
            Mptr += 64;
            mreg0 = *(const int2*)Mptr;
            mreg1 = *(const int2*)(Mptr + 32);
        }

        // two independent swapped-score chains: D[key][q], K=16 head dim
        bf16x8 kf0 = *(const bf16x8*)&Kt[qq * 136 + hh * 16 + hi * 8];
        bf16x8 kf1 = *(const bf16x8*)&Kt[(32 + qq) * 136 + hh * 16 + hi * 8];
        f32x16 c0, c1;
#pragma unroll
        for (int blk = 0; blk < 4; ++blk) {
            f32x4 m0 = *(const f32x4*)&Mf[qq * 68 + 8 * blk + 4 * hi];
            f32x4 m1 = *(const f32x4*)&Mf[qq * 68 + 32 + 8 * blk + 4 * hi];
            c0[4 * blk + 0] = m0.x;  c0[4 * blk + 1] = m0.y;
            c0[4 * blk + 2] = m0.z;  c0[4 * blk + 3] = m0.w;
            c1[4 * blk + 0] = m1.x;  c1[4 * blk + 1] = m1.y;
            c1[4 * blk + 2] = m1.z;  c1[4 * blk + 3] = m1.w;
        }
        f32x16 s0 = MFMA32(kf0, qf, c0);
        f32x16 s1 = MFMA32(kf1, qf, c1);

        bf16x8 vf0 = *(const bf16x8*)&Vtt[(hh * 16 + c) * 72 + hi * 8];
        bf16x8 vf1 = *(const bf16x8*)&Vtt[(hh * 16 + c) * 72 + 16 + hi * 8];
        bf16x8 vf2 = *(const bf16x8*)&Vtt[(hh * 16 + c) * 72 + 32 + hi * 8];
        bf16x8 vf3 = *(const bf16x8*)&Vtt[(hh * 16 + c) * 72 + 48 + hi * 8];

        // chunk 0: exp -> lsum -> pack -> PV (keys 0..31), all in-register
#pragma unroll
        for (int r = 0; r < 16; ++r) s0[r] = __builtin_amdgcn_exp2f(s0[r]);
        lsum += ((s0[0] + s0[1]) + (s0[2] + s0[3])) + ((s0[4] + s0[5]) + (s0[6] + s0[7])) +
                (((s0[8] + s0[9]) + (s0[10] + s0[11])) + ((s0[12] + s0[13]) + (s0[14] + s0[15])));
        {
            int4 pa, pb;
            pa.x = (int)pk2bf(s0[0],  s0[1]);  pa.y = (int)pk2bf(s0[2],  s0[3]);
            pa.z = (int)pk2bf(s0[4],  s0[5]);  pa.w = (int)pk2bf(s0[6],  s0[7]);
            pb.x = (int)pk2bf(s0[8],  s0[9]);  pb.y = (int)pk2bf(s0[10], s0[11]);
            pb.z = (int)pk2bf(s0[12], s0[13]); pb.w = (int)pk2bf(s0[14], s0[15]);
            bf16x8 p0, p1;
            __builtin_memcpy(&p0, &pa, 16);
            __builtin_memcpy(&p1, &pb, 16);
            O32 = MFMA32(vf0, p0, O32);
            O32 = MFMA32(vf1, p1, O32);
        }

        // chunk 1: keys 32..63
#pragma unroll
        for (int r = 0; r < 16; ++r) s1[r] = __builtin_amdgcn_exp2f(s1[r]);
        lsum += ((s1[0] + s1[1]) + (s1[2] + s1[3])) + ((s1[4] + s1[5]) + (s1[6] + s1[7])) +
                (((s1[8] + s1[9]) + (s1[10] + s1[11])) + ((s1[12] + s1[13]) + (s1[14] + s1[15])));
        {
            int4 pa, pb;
            pa.x = (int)pk2bf(s1[0],  s1[1]);  pa.y = (int)pk2bf(s1[2],  s1[3]);
            pa.z = (int)pk2bf(s1[4],  s1[5]);  pa.w = (int)pk2bf(s1[6],  s1[7]);
            pb.x = (int)pk2bf(s1[8],  s1[9]);  pb.y = (int)pk2bf(s1[10], s1[11]);
            pb.z = (int)pk2bf(s1[12], s1[13]); pb.w = (int)pk2bf(s1[14], s1[15]);
            bf16x8 p2, p3;
            __builtin_memcpy(&p2, &pa, 16);
            __builtin_memcpy(&p3, &pb, 16);
            O32 = MFMA32(vf2, p2, O32);
            O32 = MFMA32(vf3, p3, O32);
        }
    }

    // per-lane q-row denominator: combine hi halves
    lsum += __shfl_xor(lsum, 32);
    float rl = (lsum > 0.f) ? 1.f / lsum : 0.f;

    // O32 reg r (r<8) holds O^T[dim][q=qq]: dims r<4: 4hi+r ; r>=4: 8+4hi+(r-4)
    u32 h0 = pk2bf(O32[0] * rl, O32[1] * rl);
    u32 h1 = pk2bf(O32[2] * rl, O32[3] * rl);
    u32 h2 = pk2bf(O32[4] * rl, O32[5] * rl);
    u32 h3 = pk2bf(O32[6] * rl, O32[7] * rl);
    __syncthreads();                    // all Kt/Vtt reads done (Hs aliases Kt)
    u16* Hs = Kt;
    int2 ha; ha.x = (int)h0; ha.y = (int)h1;
    int2 hb; hb.x = (int)h2; hb.y = (int)h3;
    *(int2*)&Hs[qq * 136 + hh * 16 + 4 * hi]     = ha;
    *(int2*)&Hs[qq * 136 + hh * 16 + 8 + 4 * hi] = hb;
    __syncthreads();

    // fused out-projection: wave hh computes out cols hh*16..+15
    const f32x4 zf = {0.f, 0.f, 0.f, 0.f};
    f32x4 oacc[2] = {zf, zf};
#pragma unroll
    for (int kt = 0; kt < 4; ++kt) {
        bf16x8 bfr = *(const bf16x8*)&Wob[(hh * 16 + c) * 128 + kt * 32 + quad * 8];
#pragma unroll
        for (int s = 0; s < 2; ++s) {
            bf16x8 af = *(const bf16x8*)&Hs[(s * 16 + c) * 136 + kt * 32 + quad * 8];
            oacc[s] = MFMA16(af, bfr, oacc[s]);
        }
    }
#pragma unroll
    for (int s = 0; s < 2; ++s)
#pragma unroll
        for (int r = 0; r < 4; ++r)
            out[((size_t)b * NQ + q0 + s * 16 + quad * 4 + r) * 128 + hh * 16 + c] =
                oacc[s][r];
}

extern "C" void kernel_launch(void* const* d_in, const int* in_sizes, int n_in,
                              void* d_out, int out_size, void* d_ws, size_t ws_size,
                              hipStream_t stream) {
    const float* q    = (const float*)d_in[0];
    const float* h    = (const float*)d_in[1];
    const int*   mask = (const int*)d_in[2];
    const float* Wq   = (const float*)d_in[3];
    const float* Wk   = (const float*)d_in[4];
    const float* Wv   = (const float*)d_in[5];
    const float* Wout = (const float*)d_in[6];
    float* out = (float*)d_out;

    const size_t NTOK = (size_t)NB * NQ;     // 32768
    u16* Qb  = (u16*)d_ws;                   // 8 MB each
    u16* Kb  = Qb + NTOK * 128;
    u16* Vtg = Kb + NTOK * 128;              // V^T per batch, sigma-permuted slots
    u16* Wob = Vtg + NTOK * 128;             // prepped Wout, 32 KB

    proj_mfma<<<dim3(256, 4), 256, 0, stream>>>(q, h, Wq, Wk, Wv, Wout,
                                                Qb, Kb, Vtg, Wob);
    flash_mfma<<<dim3(NB, NQ / 32), 512, 0, stream>>>(Qb, Kb, Vtg, mask,
                                                      Wob, out);
}